// Round 3
// baseline (31.997 us; speedup 1.0000x reference)
//
#include <hip/hip_runtime.h>

#define BS 8
#define NN 1024
#define JJ 4
#define FF 32
#define NC 2

typedef float f4v __attribute__((ext_vector_type(4)));

// y[b][m][j][c] = sum_f x[b,m,f] * fc_w[c, j*FF+f]
// Deinterleaved: yA[bm] = (j0c0,j0c1,j1c0,j1c1), yB[bm] = (j2c0,j2c1,j3c0,j3c1)
__global__ void __launch_bounds__(256) compute_y_kernel(
    const float* __restrict__ x, const float* __restrict__ fc_w,
    float2* __restrict__ yA, float2* __restrict__ yB) {
    int idx = blockIdx.x * blockDim.x + threadIdx.x;  // over BS*NN*JJ = 32768
    if (idx >= BS * NN * JJ) return;
    int j  = idx & (JJ - 1);
    int bm = idx >> 2;                 // b*NN + m
    const float* xr = x + (size_t)bm * FF;
    const float* w0 = fc_w + 0 * (JJ * FF) + j * FF;
    const float* w1 = fc_w + 1 * (JJ * FF) + j * FF;
    float a0 = 0.f, a1 = 0.f;
#pragma unroll
    for (int f = 0; f < FF; ++f) {
        float xv = xr[f];
        a0 += xv * w0[f];
        a1 += xv * w1[f];
    }
    float2 v = make_float2(a0, a1);
    if (j < 2) yA[bm * 2 + j]       = v;
    else       yB[bm * 2 + (j - 2)] = v;
}

// out[b,n,c] = sum_m sum_j WW[b,n,m,j] * y[b,m,j,c] + fc_b[c]
// 256 thr = 4 waves/block, 2 rows/wave -> 8 rows/block, grid=1024 (4 blocks/CU).
// y[b] staged in LDS (32 KB). WW streamed with a depth-2 register pipeline:
// 16 float4 loads in flight per wave sustained.
__global__ void __launch_bounds__(256, 4) reduce_out_kernel(
    const float* __restrict__ WW, const float4* __restrict__ yA,
    const float4* __restrict__ yB, const float* __restrict__ fc_b,
    float* __restrict__ out) {
    __shared__ float4 lyA[NN];
    __shared__ float4 lyB[NN];

    const int blk  = blockIdx.x;          // 0..1023
    const int b    = blk >> 7;            // 128 blocks per batch element
    const int wave = threadIdx.x >> 6;
    const int lane = threadIdx.x & 63;

    for (int i = threadIdx.x; i < NN; i += 256) {
        lyA[i] = yA[(size_t)b * NN + i];
        lyB[i] = yB[(size_t)b * NN + i];
    }
    __syncthreads();

    const int row0 = blk * 8 + wave * 2;
    const f4v* W0 = reinterpret_cast<const f4v*>(WW) + (size_t)row0 * NN;
    const f4v* W1 = W0 + NN;

    float s00 = 0.f, s01 = 0.f, s10 = 0.f, s11 = 0.f;
    f4v pa0[4], pa1[4], pb0[4], pb1[4];  // two in-flight batches (A, B)

    // prologue: issue batches 0 and 1 (16 loads in flight)
#pragma unroll
    for (int u = 0; u < 4; ++u) { int m = lane + 64 * u;       pa0[u] = W0[m]; pa1[u] = W1[m]; }
#pragma unroll
    for (int u = 0; u < 4; ++u) { int m = lane + 64 * (4 + u); pb0[u] = W0[m]; pb1[u] = W1[m]; }

    // ---- consume batch 0 (regs A), then refill A with batch 2 ----
#pragma unroll
    for (int u = 0; u < 4; ++u) {
        int m = lane + 64 * u;
        float4 ya = lyA[m], yb = lyB[m];
        s00 += pa0[u].x * ya.x + pa0[u].y * ya.z + pa0[u].z * yb.x + pa0[u].w * yb.z;
        s01 += pa0[u].x * ya.y + pa0[u].y * ya.w + pa0[u].z * yb.y + pa0[u].w * yb.w;
        s10 += pa1[u].x * ya.x + pa1[u].y * ya.z + pa1[u].z * yb.x + pa1[u].w * yb.z;
        s11 += pa1[u].x * ya.y + pa1[u].y * ya.w + pa1[u].z * yb.y + pa1[u].w * yb.w;
    }
#pragma unroll
    for (int u = 0; u < 4; ++u) { int m = lane + 64 * (8 + u); pa0[u] = W0[m]; pa1[u] = W1[m]; }

    // ---- consume batch 1 (regs B), then refill B with batch 3 ----
#pragma unroll
    for (int u = 0; u < 4; ++u) {
        int m = lane + 64 * (4 + u);
        float4 ya = lyA[m], yb = lyB[m];
        s00 += pb0[u].x * ya.x + pb0[u].y * ya.z + pb0[u].z * yb.x + pb0[u].w * yb.z;
        s01 += pb0[u].x * ya.y + pb0[u].y * ya.w + pb0[u].z * yb.y + pb0[u].w * yb.w;
        s10 += pb1[u].x * ya.x + pb1[u].y * ya.z + pb1[u].z * yb.x + pb1[u].w * yb.z;
        s11 += pb1[u].x * ya.y + pb1[u].y * ya.w + pb1[u].z * yb.y + pb1[u].w * yb.w;
    }
#pragma unroll
    for (int u = 0; u < 4; ++u) { int m = lane + 64 * (12 + u); pb0[u] = W0[m]; pb1[u] = W1[m]; }

    // ---- consume batch 2 (regs A) ----
#pragma unroll
    for (int u = 0; u < 4; ++u) {
        int m = lane + 64 * (8 + u);
        float4 ya = lyA[m], yb = lyB[m];
        s00 += pa0[u].x * ya.x + pa0[u].y * ya.z + pa0[u].z * yb.x + pa0[u].w * yb.z;
        s01 += pa0[u].x * ya.y + pa0[u].y * ya.w + pa0[u].z * yb.y + pa0[u].w * yb.w;
        s10 += pa1[u].x * ya.x + pa1[u].y * ya.z + pa1[u].z * yb.x + pa1[u].w * yb.z;
        s11 += pa1[u].x * ya.y + pa1[u].y * ya.w + pa1[u].z * yb.y + pa1[u].w * yb.w;
    }
    // ---- consume batch 3 (regs B) ----
#pragma unroll
    for (int u = 0; u < 4; ++u) {
        int m = lane + 64 * (12 + u);
        float4 ya = lyA[m], yb = lyB[m];
        s00 += pb0[u].x * ya.x + pb0[u].y * ya.z + pb0[u].z * yb.x + pb0[u].w * yb.z;
        s01 += pb0[u].x * ya.y + pb0[u].y * ya.w + pb0[u].z * yb.y + pb0[u].w * yb.w;
        s10 += pb1[u].x * ya.x + pb1[u].y * ya.z + pb1[u].z * yb.x + pb1[u].w * yb.z;
        s11 += pb1[u].x * ya.y + pb1[u].y * ya.w + pb1[u].z * yb.y + pb1[u].w * yb.w;
    }

#pragma unroll
    for (int off = 32; off > 0; off >>= 1) {
        s00 += __shfl_down(s00, off, 64);
        s01 += __shfl_down(s01, off, 64);
        s10 += __shfl_down(s10, off, 64);
        s11 += __shfl_down(s11, off, 64);
    }
    if (lane == 0) {
        float b0 = fc_b[0], b1 = fc_b[1];
        out[(size_t)row0 * NC + 0] = s00 + b0;
        out[(size_t)row0 * NC + 1] = s01 + b1;
        out[(size_t)(row0 + 1) * NC + 0] = s10 + b0;
        out[(size_t)(row0 + 1) * NC + 1] = s11 + b1;
    }
}

extern "C" void kernel_launch(void* const* d_in, const int* in_sizes, int n_in,
                              void* d_out, int out_size, void* d_ws, size_t ws_size,
                              hipStream_t stream) {
    const float* WW   = (const float*)d_in[0];  // (BS, NN, NN, JJ) fp32
    const float* x    = (const float*)d_in[1];  // (BS, NN, FF) fp32
    const float* fc_w = (const float*)d_in[2];  // (NC, JJ*FF) fp32
    const float* fc_b = (const float*)d_in[3];  // (NC,) fp32
    float* out = (float*)d_out;                 // (BS, NN, NC) fp32

    float* ws  = (float*)d_ws;
    float2* yA2 = (float2*)ws;
    float2* yB2 = (float2*)(ws + (size_t)BS * NN * 4);

    {
        int total = BS * NN * JJ;
        compute_y_kernel<<<(total + 255) / 256, 256, 0, stream>>>(x, fc_w, yA2, yB2);
    }
    {
        int blocks = (BS * NN) / 8;  // 1024
        reduce_out_kernel<<<blocks, 256, 0, stream>>>(
            WW, (const float4*)yA2, (const float4*)yB2, fc_b, out);
    }
}